// Round 8
// baseline (127.097 us; speedup 1.0000x reference)
//
#include <hip/hip_runtime.h>
#include <hip/hip_bf16.h>

// Problem constants
#define DIM_X 256
#define DIM_E 256
#define DD    512          // DIM_X + DIM_E
#define NB    8            // batch
#define NN    2048         // sequence
#define SCALE 0.044194173824159216f   // (DIM_X+DIM_E)^-0.5
#define MAGIC 0x13579BDFu

typedef __attribute__((ext_vector_type(8))) __bf16 bf16x8;
typedef __attribute__((ext_vector_type(4))) float  f32x4;
using bf16 = __hip_bfloat16;

__device__ __forceinline__ unsigned short f2bf(float f) {
  union { __hip_bfloat16 h; unsigned short u; } c;
  c.h = __float2bfloat16(f);
  return c.u;
}

// async global->LDS 16B copy. LDS dest must be wave-uniform base + lane*16.
__device__ __forceinline__ void async_lds16(const void* g, void* l) {
  using u32_as3 = __attribute__((address_space(3))) unsigned int;
  using u32_as1 = const __attribute__((address_space(1))) unsigned int;
  __builtin_amdgcn_global_load_lds(
      reinterpret_cast<u32_as1*>(reinterpret_cast<unsigned long long>(g)),
      reinterpret_cast<u32_as3*>(static_cast<unsigned int>(
          reinterpret_cast<unsigned long long>(l))),
      16, 0, 0);
}

// ---------------------------------------------------------------------------
// Flag protocol (producer->consumer ordering inside one kernel).
// Caller must __syncthreads() (drains all waves' stores) before flag_set.
// Flags are 64B-spaced uints in ws; harness re-poisons ws to 0xAA != MAGIC
// before every launch, so no initialization pass is needed.
// ---------------------------------------------------------------------------
__device__ __forceinline__ void flag_set(unsigned* flags, int i) {
  if (threadIdx.x == 0) {
    __threadfence();  // agent release: make tile stores visible cross-XCD
    __hip_atomic_store(&flags[i * 16], MAGIC, __ATOMIC_RELAXED,
                       __HIP_MEMORY_SCOPE_AGENT);
  }
}
__device__ __forceinline__ void flag_wait8(unsigned* flags, int base,
                                           int stride) {
  if (threadIdx.x == 0) {
#pragma unroll 1
    for (int k = 0; k < 8; k++)
      while (__hip_atomic_load(&flags[(base + k * stride) * 16],
                               __ATOMIC_RELAXED,
                               __HIP_MEMORY_SCOPE_AGENT) != MAGIC)
        __builtin_amdgcn_s_sleep(2);
    __threadfence();  // agent acquire: invalidate stale L1/L2 lines
  }
  __syncthreads();
}

// ---------------------------------------------------------------------------
// pack: 5120 32x32-tile jobs over 1024 blocks (5 each):
//   jobs [0,4096):     x -> xb (straight bf16) + VT (transpose)
//   jobs [4096,4608):  e -> eb (straight) + ET (transpose)
//   jobs [4608,4864):  Wq -> WqT (transpose)
//   jobs [4864,5120):  Wk -> WkT (transpose)
// ---------------------------------------------------------------------------
__global__ __launch_bounds__(256, 4) void pack_k(
    const float* __restrict__ x, const float* __restrict__ e,
    const float* __restrict__ Wq, const float* __restrict__ Wk, bf16* xb,
    bf16* VT, bf16* eb, bf16* ET, bf16* WqT, bf16* WkT) {
  __shared__ float tile[32][33];
  const int tid  = threadIdx.x;
  const int lrow = tid >> 3;        // 0..31 (load row)
  const int lc4  = (tid & 7) * 4;   // float4 col
  for (int j = blockIdx.x; j < 5120; j += 1024) {
    const float* src; int ld;
    bf16 *dS = nullptr, *dT; int ldS = 0, ldT;
    if (j < 4096) {
      int b = j >> 9, r = (j >> 3) & 63, c = j & 7;
      src = x + ((long)b * NN + r * 32) * DIM_X + c * 32; ld = DIM_X;
      dS = xb + ((long)b * NN + r * 32) * DIM_X + c * 32; ldS = DIM_X;
      dT = VT + ((long)b * DIM_X + c * 32) * NN + r * 32; ldT = NN;
    } else if (j < 4608) {
      int i = j - 4096, r = i >> 3, c = i & 7;
      src = e + ((long)r * 32) * DIM_E + c * 32; ld = DIM_E;
      dS = eb + ((long)r * 32) * DIM_E + c * 32; ldS = DIM_E;
      dT = ET + ((long)c * 32) * NN + r * 32; ldT = NN;
    } else if (j < 4864) {
      int i = j - 4608, r = i >> 4, c = i & 15;
      src = Wq + ((long)r * 32) * DD + c * 32; ld = DD;
      dT = WqT + ((long)c * 32) * DD + r * 32; ldT = DD;
    } else {
      int i = j - 4864, r = i >> 4, c = i & 15;
      src = Wk + ((long)r * 32) * DD + c * 32; ld = DD;
      dT = WkT + ((long)c * 32) * DD + r * 32; ldT = DD;
    }
    float4 v = *(const float4*)(src + (long)lrow * ld + lc4);
    if (dS) {
      ushort4 o;
      o.x = f2bf(v.x); o.y = f2bf(v.y); o.z = f2bf(v.z); o.w = f2bf(v.w);
      *(ushort4*)((unsigned short*)dS + (long)lrow * ldS + lc4) = o;
    }
    tile[lrow][lc4 + 0] = v.x; tile[lrow][lc4 + 1] = v.y;
    tile[lrow][lc4 + 2] = v.z; tile[lrow][lc4 + 3] = v.w;
    __syncthreads();
    {
      ushort4 o;
      o.x = f2bf(tile[lc4 + 0][lrow]);
      o.y = f2bf(tile[lc4 + 1][lrow]);
      o.z = f2bf(tile[lc4 + 2][lrow]);
      o.w = f2bf(tile[lc4 + 3][lrow]);
      *(ushort4*)((unsigned short*)dT + (long)lrow * ldT + lc4) = o;
    }
    __syncthreads();
  }
}

// ---------------------------------------------------------------------------
// One BMxBN tile of C = alpha * A @ B^T (operands K-major bf16).
// 4 waves 2x2, wave tile (BM/2)x(BN/2), 16x16x32 MFMA, XOR-swizzled LDS,
// global_load_lds width-16 staging, K-tile BKt (64 or 128).
// A1 (if non-null): A columns k>=256 (same leading dim as A0).
// ---------------------------------------------------------------------------
template <int BM, int BN, int BKt, bool OUT_BF16>
__device__ void gemm_tile(const bf16* __restrict__ A0,
                          const bf16* __restrict__ A1,
                          const bf16* __restrict__ B, void* __restrict__ Cv,
                          int K, int lda, int ldb, int ldc, float alpha,
                          char* smem) {
  constexpr int CPT = BKt / 8;       // 16B chunks per row
  constexpr int KS  = BKt / 32;      // MFMA k-steps per staged tile
  constexpr int WTM = BM / 2, WTN = BN / 2;
  constexpr int IM = WTM / 16, IN = WTN / 16;
  constexpr int CA = BM * CPT, CB = BN * CPT;
  bf16* sA = (bf16*)smem;
  bf16* sB = (bf16*)(smem + (size_t)BM * BKt * 2);

  const int tid  = threadIdx.x;
  const int lane = tid & 63;
  const int wave = tid >> 6;
  const int lm   = lane & 15;
  const int quad = lane >> 4;
  const int wm   = (wave >> 1) * WTM;
  const int wn   = (wave & 1) * WTN;

  f32x4 acc[IM][IN];
#pragma unroll
  for (int i = 0; i < IM; i++)
#pragma unroll
    for (int j = 0; j < IN; j++) acc[i][j] = (f32x4){0.f, 0.f, 0.f, 0.f};

  for (int k0 = 0; k0 < K; k0 += BKt) {
    const bf16* Ak = A0; int kk = k0;
    if (A1 != nullptr && k0 >= 256) { Ak = A1; kk = k0 - 256; }
#pragma unroll
    for (int c = tid; c < CA; c += 256) {
      int row = c / CPT;
      int cb  = (c % CPT) ^ (row % CPT);
      async_lds16(Ak + (long)row * lda + kk + cb * 8, sA + (size_t)c * 8);
    }
#pragma unroll
    for (int c = tid; c < CB; c += 256) {
      int row = c / CPT;
      int cb  = (c % CPT) ^ (row % CPT);
      async_lds16(B + (long)row * ldb + k0 + cb * 8, sB + (size_t)c * 8);
    }
    __syncthreads();  // drains vmcnt (global_load_lds)

    bf16x8 af[KS][IM], bfr[KS][IN];
#pragma unroll
    for (int s = 0; s < KS; s++) {
#pragma unroll
      for (int i = 0; i < IM; i++) {
        int r = wm + i * 16 + lm;
        af[s][i] = *(const bf16x8*)&sA[r * BKt +
                                       (((s * 4 + quad) ^ (r % CPT)) * 8)];
      }
#pragma unroll
      for (int j = 0; j < IN; j++) {
        int r = wn + j * 16 + lm;
        bfr[s][j] = *(const bf16x8*)&sB[r * BKt +
                                        (((s * 4 + quad) ^ (r % CPT)) * 8)];
      }
    }
#pragma unroll
    for (int s = 0; s < KS; s++)
#pragma unroll
      for (int i = 0; i < IM; i++)
#pragma unroll
        for (int j = 0; j < IN; j++)
          acc[i][j] = __builtin_amdgcn_mfma_f32_16x16x32_bf16(
              af[s][i], bfr[s][j], acc[i][j], 0, 0, 0);
    __syncthreads();
  }

  // C/D layout (16x16): col = lane&15, row = (lane>>4)*4 + reg  [m89-verified]
  const int baseRow = wm + quad * 4;
  const int baseCol = wn + lm;
  if (OUT_BF16) {
    bf16* Cb = (bf16*)Cv;
#pragma unroll
    for (int i = 0; i < IM; i++)
#pragma unroll
      for (int r = 0; r < 4; r++) {
        int row = baseRow + i * 16 + r;
#pragma unroll
        for (int j = 0; j < IN; j++)
          Cb[(long)row * ldc + baseCol + j * 16] =
              __float2bfloat16(acc[i][j][r] * alpha);
      }
  } else {
    float* Cf = (float*)Cv;
#pragma unroll
    for (int i = 0; i < IM; i++)
#pragma unroll
      for (int r = 0; r < 4; r++) {
        int row = baseRow + i * 16 + r;
#pragma unroll
        for (int j = 0; j < IN; j++)
          Cf[(long)row * ldc + baseCol + j * 16] = acc[i][j][r] * alpha;
      }
  }
}

// ---------------------------------------------------------------------------
// phase12 (320 blocks): fused M -> R with flag-based in-kernel ordering.
//  blocks 0-255:  M(b,r,c) = VT_b[r] @ [VT_b ; ET][c]^T  (64x64, K=2048),
//                 flag bx; then wait M(b,r,*) + W2T(c,*) and compute
//                 R(b,r,c) = SCALE * M_b[r] @ W2T[c]^T    (64x64, K=512).
//  blocks 256-319: W2T(r2,c2) = WqT[r2] @ WkT[c2]^T, flag 256+r2*8+c2.
//  320 blocks are all co-resident (<=1024 capacity) => no deadlock.
//  XCD swizzle b=bx&7 keeps VT_b/M_b traffic on one XCD's L2.
// ---------------------------------------------------------------------------
__global__ __launch_bounds__(256, 4) void phase12_k(
    const bf16* VT, const bf16* ET, const bf16* WqT, const bf16* WkT, bf16* M,
    bf16* W2T, bf16* R, unsigned* flags) {
  __shared__ __align__(16) char smem[32768];
  const int bx = blockIdx.x;
  if (bx < 256) {
    const int b = bx & 7, r = (bx >> 3) & 3, c = bx >> 5;
    const bf16* A = VT + (long)b * DIM_X * NN + (long)r * 64 * NN;
    const bf16* B = (c < 4) ? VT + (long)b * DIM_X * NN + (long)c * 64 * NN
                            : ET + (long)(c - 4) * 64 * NN;
    bf16* Mt = M + (long)b * DIM_X * DD + (long)r * 64 * DD + c * 64;
    gemm_tile<64, 64, 128, true>(A, nullptr, B, Mt, NN, NN, NN, DD, 1.0f,
                                 smem);
    __syncthreads();  // all waves' M stores drained (vmcnt) before release
    flag_set(flags, bx);
    // wait for the full M(b,r,*) row-slab and W2T(c,*) row-slab
    flag_wait8(flags, b + r * 8, 32);
    flag_wait8(flags, 256 + c * 8, 1);
    gemm_tile<64, 64, 128, true>(
        M + (long)b * DIM_X * DD + (long)r * 64 * DD, nullptr,
        W2T + (long)c * 64 * DD,
        R + (long)b * DIM_X * DD + (long)r * 64 * DD + c * 64, DD, DD, DD, DD,
        SCALE, smem);
  } else {
    const int i = bx - 256, r2 = i >> 3, c2 = i & 7;
    gemm_tile<64, 64, 128, true>(WqT + (long)r2 * 64 * DD, nullptr,
                                 WkT + (long)c2 * 64 * DD,
                                 W2T + (long)r2 * 64 * DD + c2 * 64, DD, DD,
                                 DD, DD, 1.0f, smem);
    __syncthreads();
    flag_set(flags, 256 + r2 * 8 + c2);
  }
}

// phase3 (1024 blocks): out_b = [xb_b | eb] @ R_b^T (64x64 tiles, K=512, fp32,
//   XCD-swizzled: b = bx&7 so xb_b + R_b stay in one XCD's L2)
__global__ __launch_bounds__(256, 4) void phase3_k(const bf16* xb,
                                                   const bf16* eb,
                                                   const bf16* R, float* out) {
  __shared__ __align__(16) char smem[32768];
  const int bx = blockIdx.x;
  int b = bx & 7, m = (bx >> 3) & 31, n = bx >> 8;
  gemm_tile<64, 64, 128, false>(
      xb + (long)b * NN * DIM_X + (long)m * 64 * DIM_X,
      eb + (long)m * 64 * DIM_E,
      R + (long)b * DIM_X * DD + (long)n * 64 * DD,
      out + (long)b * NN * DIM_X + (long)m * 64 * DIM_X + n * 64, DD, DIM_X,
      DD, DIM_X, 1.0f, smem);
}

// ---------------------------------------------------------------------------

extern "C" void kernel_launch(void* const* d_in, const int* in_sizes, int n_in,
                              void* d_out, int out_size, void* d_ws,
                              size_t ws_size, hipStream_t stream) {
  const float* x  = (const float*)d_in[0];  // (8, 2048, 256)
  const float* e  = (const float*)d_in[1];  // (2048, 256)
  const float* Wq = (const float*)d_in[2];  // (512, 512)
  const float* Wk = (const float*)d_in[3];  // (512, 512)
  float* out = (float*)d_out;               // (8, 2048, 256)

  char* ws = (char*)d_ws;
  size_t off = 0;
  auto alloc = [&](size_t bytes) {
    void* p = ws + off;
    off += (bytes + 255) & ~(size_t)255;
    return p;
  };

  bf16* xb  = (bf16*)alloc((size_t)NB * NN * DIM_X * 2);  // 8.4 MB
  bf16* VT  = (bf16*)alloc((size_t)NB * DIM_X * NN * 2);  // 8.4 MB
  bf16* eb  = (bf16*)alloc((size_t)NN * DIM_E * 2);       // 1 MB
  bf16* ET  = (bf16*)alloc((size_t)DIM_E * NN * 2);       // 1 MB
  bf16* WqT = (bf16*)alloc((size_t)DD * DD * 2);          // 0.5 MB
  bf16* WkT = (bf16*)alloc((size_t)DD * DD * 2);          // 0.5 MB
  bf16* W2T = (bf16*)alloc((size_t)DD * DD * 2);          // 0.5 MB
  bf16* M   = (bf16*)alloc((size_t)NB * DIM_X * DD * 2);  // 2 MB
  bf16* R   = (bf16*)alloc((size_t)NB * DIM_X * DD * 2);  // 2 MB
  unsigned* flags = (unsigned*)alloc(320 * 64);           // 20 KB (64B-spaced)

  pack_k<<<1024, 256, 0, stream>>>(x, e, Wq, Wk, xb, VT, eb, ET, WqT, WkT);
  phase12_k<<<320, 256, 0, stream>>>(VT, ET, WqT, WkT, M, W2T, R, flags);
  phase3_k<<<1024, 256, 0, stream>>>(xb, eb, R, out);
}

// Round 9
// 106.067 us; speedup vs baseline: 1.1983x; 1.1983x over previous
//
#include <hip/hip_runtime.h>
#include <hip/hip_bf16.h>

// Problem constants
#define DIM_X 256
#define DIM_E 256
#define DD    512          // DIM_X + DIM_E
#define NB    8            // batch
#define NN    2048         // sequence
#define SCALE 0.044194173824159216f   // (DIM_X+DIM_E)^-0.5

typedef __attribute__((ext_vector_type(8))) __bf16 bf16x8;
typedef __attribute__((ext_vector_type(4))) float  f32x4;
using bf16 = __hip_bfloat16;

__device__ __forceinline__ unsigned short f2bf(float f) {
  union { __hip_bfloat16 h; unsigned short u; } c;
  c.h = __float2bfloat16(f);
  return c.u;
}

// async global->LDS 16B copy. LDS dest must be wave-uniform base + lane*16.
__device__ __forceinline__ void async_lds16(const void* g, void* l) {
  using u32_as3 = __attribute__((address_space(3))) unsigned int;
  using u32_as1 = const __attribute__((address_space(1))) unsigned int;
  __builtin_amdgcn_global_load_lds(
      reinterpret_cast<u32_as1*>(reinterpret_cast<unsigned long long>(g)),
      reinterpret_cast<u32_as3*>(static_cast<unsigned int>(
          reinterpret_cast<unsigned long long>(l))),
      16, 0, 0);
}

// ---------------------------------------------------------------------------
// pack: 5120 32x32-tile jobs over 1024 blocks (5 each):
//   jobs [0,4096):     x -> xb (straight bf16) + VT (transpose)
//   jobs [4096,4608):  e -> eb (straight) + ET (transpose)
//   jobs [4608,4864):  Wq -> WqT (transpose)
//   jobs [4864,5120):  Wk -> WkT (transpose)
// ---------------------------------------------------------------------------
__global__ __launch_bounds__(256, 4) void pack_k(
    const float* __restrict__ x, const float* __restrict__ e,
    const float* __restrict__ Wq, const float* __restrict__ Wk, bf16* xb,
    bf16* VT, bf16* eb, bf16* ET, bf16* WqT, bf16* WkT) {
  __shared__ float tile[32][33];
  const int tid  = threadIdx.x;
  const int lrow = tid >> 3;        // 0..31 (load row)
  const int lc4  = (tid & 7) * 4;   // float4 col
  for (int j = blockIdx.x; j < 5120; j += 1024) {
    const float* src; int ld;
    bf16 *dS = nullptr, *dT; int ldS = 0, ldT;
    if (j < 4096) {
      int b = j >> 9, r = (j >> 3) & 63, c = j & 7;
      src = x + ((long)b * NN + r * 32) * DIM_X + c * 32; ld = DIM_X;
      dS = xb + ((long)b * NN + r * 32) * DIM_X + c * 32; ldS = DIM_X;
      dT = VT + ((long)b * DIM_X + c * 32) * NN + r * 32; ldT = NN;
    } else if (j < 4608) {
      int i = j - 4096, r = i >> 3, c = i & 7;
      src = e + ((long)r * 32) * DIM_E + c * 32; ld = DIM_E;
      dS = eb + ((long)r * 32) * DIM_E + c * 32; ldS = DIM_E;
      dT = ET + ((long)c * 32) * NN + r * 32; ldT = NN;
    } else if (j < 4864) {
      int i = j - 4608, r = i >> 4, c = i & 15;
      src = Wq + ((long)r * 32) * DD + c * 32; ld = DD;
      dT = WqT + ((long)c * 32) * DD + r * 32; ldT = DD;
    } else {
      int i = j - 4864, r = i >> 4, c = i & 15;
      src = Wk + ((long)r * 32) * DD + c * 32; ld = DD;
      dT = WkT + ((long)c * 32) * DD + r * 32; ldT = DD;
    }
    float4 v = *(const float4*)(src + (long)lrow * ld + lc4);
    if (dS) {
      ushort4 o;
      o.x = f2bf(v.x); o.y = f2bf(v.y); o.z = f2bf(v.z); o.w = f2bf(v.w);
      *(ushort4*)((unsigned short*)dS + (long)lrow * ldS + lc4) = o;
    }
    tile[lrow][lc4 + 0] = v.x; tile[lrow][lc4 + 1] = v.y;
    tile[lrow][lc4 + 2] = v.z; tile[lrow][lc4 + 3] = v.w;
    __syncthreads();
    {
      ushort4 o;
      o.x = f2bf(tile[lc4 + 0][lrow]);
      o.y = f2bf(tile[lc4 + 1][lrow]);
      o.z = f2bf(tile[lc4 + 2][lrow]);
      o.w = f2bf(tile[lc4 + 3][lrow]);
      *(ushort4*)((unsigned short*)dT + (long)lrow * ldT + lc4) = o;
    }
    __syncthreads();
  }
}

// ---------------------------------------------------------------------------
// One BMxBN tile of C = alpha * A @ B^T (operands K-major bf16).
// 4 waves 2x2, wave tile (BM/2)x(BN/2), 16x16x32 MFMA, XOR-swizzled LDS,
// global_load_lds width-16 staging, K-tile BKt.
// A1 (if non-null): A columns k>=256 (same leading dim as A0).
// ---------------------------------------------------------------------------
template <int BM, int BN, int BKt, bool OUT_BF16>
__device__ void gemm_tile(const bf16* __restrict__ A0,
                          const bf16* __restrict__ A1,
                          const bf16* __restrict__ B, void* __restrict__ Cv,
                          int K, int lda, int ldb, int ldc, float alpha,
                          char* smem) {
  constexpr int CPT = BKt / 8;       // 16B chunks per row
  constexpr int KS  = BKt / 32;      // MFMA k-steps per staged tile
  constexpr int WTM = BM / 2, WTN = BN / 2;
  constexpr int IM = WTM / 16, IN = WTN / 16;
  constexpr int CA = BM * CPT, CB = BN * CPT;
  bf16* sA = (bf16*)smem;
  bf16* sB = (bf16*)(smem + (size_t)BM * BKt * 2);

  const int tid  = threadIdx.x;
  const int lane = tid & 63;
  const int wave = tid >> 6;
  const int lm   = lane & 15;
  const int quad = lane >> 4;
  const int wm   = (wave >> 1) * WTM;
  const int wn   = (wave & 1) * WTN;

  f32x4 acc[IM][IN];
#pragma unroll
  for (int i = 0; i < IM; i++)
#pragma unroll
    for (int j = 0; j < IN; j++) acc[i][j] = (f32x4){0.f, 0.f, 0.f, 0.f};

  for (int k0 = 0; k0 < K; k0 += BKt) {
    const bf16* Ak = A0; int kk = k0;
    if (A1 != nullptr && k0 >= 256) { Ak = A1; kk = k0 - 256; }
#pragma unroll
    for (int c = tid; c < CA; c += 256) {
      int row = c / CPT;
      int cb  = (c % CPT) ^ (row % CPT);
      async_lds16(Ak + (long)row * lda + kk + cb * 8, sA + (size_t)c * 8);
    }
#pragma unroll
    for (int c = tid; c < CB; c += 256) {
      int row = c / CPT;
      int cb  = (c % CPT) ^ (row % CPT);
      async_lds16(B + (long)row * ldb + k0 + cb * 8, sB + (size_t)c * 8);
    }
    __syncthreads();  // drains vmcnt (global_load_lds)

    bf16x8 af[KS][IM], bfr[KS][IN];
#pragma unroll
    for (int s = 0; s < KS; s++) {
#pragma unroll
      for (int i = 0; i < IM; i++) {
        int r = wm + i * 16 + lm;
        af[s][i] = *(const bf16x8*)&sA[r * BKt +
                                       (((s * 4 + quad) ^ (r % CPT)) * 8)];
      }
#pragma unroll
      for (int j = 0; j < IN; j++) {
        int r = wn + j * 16 + lm;
        bfr[s][j] = *(const bf16x8*)&sB[r * BKt +
                                        (((s * 4 + quad) ^ (r % CPT)) * 8)];
      }
    }
#pragma unroll
    for (int s = 0; s < KS; s++)
#pragma unroll
      for (int i = 0; i < IM; i++)
#pragma unroll
        for (int j = 0; j < IN; j++)
          acc[i][j] = __builtin_amdgcn_mfma_f32_16x16x32_bf16(
              af[s][i], bfr[s][j], acc[i][j], 0, 0, 0);
    __syncthreads();
  }

  // C/D layout (16x16): col = lane&15, row = (lane>>4)*4 + reg  [m89-verified]
  const int baseRow = wm + quad * 4;
  const int baseCol = wn + lm;
  if (OUT_BF16) {
    bf16* Cb = (bf16*)Cv;
#pragma unroll
    for (int i = 0; i < IM; i++)
#pragma unroll
      for (int r = 0; r < 4; r++) {
        int row = baseRow + i * 16 + r;
#pragma unroll
        for (int j = 0; j < IN; j++)
          Cb[(long)row * ldc + baseCol + j * 16] =
              __float2bfloat16(acc[i][j][r] * alpha);
      }
  } else {
    float* Cf = (float*)Cv;
#pragma unroll
    for (int i = 0; i < IM; i++)
#pragma unroll
      for (int r = 0; r < 4; r++) {
        int row = baseRow + i * 16 + r;
#pragma unroll
        for (int j = 0; j < IN; j++)
          Cf[(long)row * ldc + baseCol + j * 16] = acc[i][j][r] * alpha;
      }
  }
}

// ---------------------------------------------------------------------------
// phase1 (576 blocks): M_b = VT_b @ [VT_b ; ET]^T  (512 jobs, 32x64, K=2048,
//   BK=128, XCD-swizzled b=bx&7 so VT_b (4MB) stays in one XCD's L2;
//   512 blocks => 2 blocks/CU for latency hiding)
//   + W2T = WqT @ WkT^T (64 jobs, 64x64, K=512)
// ---------------------------------------------------------------------------
__global__ __launch_bounds__(256, 4) void phase1_k(const bf16* VT,
                                                   const bf16* ET,
                                                   const bf16* WqT,
                                                   const bf16* WkT, bf16* M,
                                                   bf16* W2T) {
  __shared__ __align__(16) char smem[32768];
  const int bx = blockIdx.x;
  if (bx < 512) {
    int b = bx & 7, r = (bx >> 3) & 7, c = bx >> 6;
    const bf16* A = VT + (long)b * DIM_X * NN + (long)r * 32 * NN;
    const bf16* B = (c < 4) ? VT + (long)b * DIM_X * NN + (long)c * 64 * NN
                            : ET + (long)(c - 4) * 64 * NN;
    gemm_tile<32, 64, 128, true>(
        A, nullptr, B, M + (long)b * DIM_X * DD + (long)r * 32 * DD + c * 64,
        NN, NN, NN, DD, 1.0f, smem);
  } else {
    int i = bx - 512, r2 = i >> 3, c2 = i & 7;
    gemm_tile<64, 64, 128, true>(WqT + (long)r2 * 64 * DD, nullptr,
                                 WkT + (long)c2 * 64 * DD,
                                 W2T + (long)r2 * 64 * DD + c2 * 64, DD, DD,
                                 DD, DD, 1.0f, smem);
  }
}

// phase2 (512 blocks): R_b = SCALE * M_b @ W2T^T (32x64 tiles, K=512, BK=128)
__global__ __launch_bounds__(256, 4) void phase2_k(const bf16* M,
                                                   const bf16* W2T, bf16* R) {
  __shared__ __align__(16) char smem[32768];
  const int bx = blockIdx.x;
  int b = bx & 7, r = (bx >> 3) & 7, c = bx >> 6;
  gemm_tile<32, 64, 128, true>(
      M + (long)b * DIM_X * DD + (long)r * 32 * DD, nullptr,
      W2T + (long)c * 64 * DD,
      R + (long)b * DIM_X * DD + (long)r * 32 * DD + c * 64, DD, DD, DD, DD,
      SCALE, smem);
}

// phase3 (1024 blocks): out_b = [xb_b | eb] @ R_b^T (64x64 tiles, K=512, fp32,
//   XCD-swizzled: b = bx&7 so xb_b + R_b stay in one XCD's L2)
__global__ __launch_bounds__(256, 4) void phase3_k(const bf16* xb,
                                                   const bf16* eb,
                                                   const bf16* R, float* out) {
  __shared__ __align__(16) char smem[32768];
  const int bx = blockIdx.x;
  int b = bx & 7, m = (bx >> 3) & 31, n = bx >> 8;
  gemm_tile<64, 64, 128, false>(
      xb + (long)b * NN * DIM_X + (long)m * 64 * DIM_X,
      eb + (long)m * 64 * DIM_E,
      R + (long)b * DIM_X * DD + (long)n * 64 * DD,
      out + (long)b * NN * DIM_X + (long)m * 64 * DIM_X + n * 64, DD, DIM_X,
      DD, DIM_X, 1.0f, smem);
}

// ---------------------------------------------------------------------------

extern "C" void kernel_launch(void* const* d_in, const int* in_sizes, int n_in,
                              void* d_out, int out_size, void* d_ws,
                              size_t ws_size, hipStream_t stream) {
  const float* x  = (const float*)d_in[0];  // (8, 2048, 256)
  const float* e  = (const float*)d_in[1];  // (2048, 256)
  const float* Wq = (const float*)d_in[2];  // (512, 512)
  const float* Wk = (const float*)d_in[3];  // (512, 512)
  float* out = (float*)d_out;               // (8, 2048, 256)

  char* ws = (char*)d_ws;
  size_t off = 0;
  auto alloc = [&](size_t bytes) {
    void* p = ws + off;
    off += (bytes + 255) & ~(size_t)255;
    return p;
  };

  bf16* xb  = (bf16*)alloc((size_t)NB * NN * DIM_X * 2);  // 8.4 MB
  bf16* VT  = (bf16*)alloc((size_t)NB * DIM_X * NN * 2);  // 8.4 MB
  bf16* eb  = (bf16*)alloc((size_t)NN * DIM_E * 2);       // 1 MB
  bf16* ET  = (bf16*)alloc((size_t)DIM_E * NN * 2);       // 1 MB
  bf16* WqT = (bf16*)alloc((size_t)DD * DD * 2);          // 0.5 MB
  bf16* WkT = (bf16*)alloc((size_t)DD * DD * 2);          // 0.5 MB
  bf16* W2T = (bf16*)alloc((size_t)DD * DD * 2);          // 0.5 MB
  bf16* M   = (bf16*)alloc((size_t)NB * DIM_X * DD * 2);  // 2 MB
  bf16* R   = (bf16*)alloc((size_t)NB * DIM_X * DD * 2);  // 2 MB

  pack_k<<<1024, 256, 0, stream>>>(x, e, Wq, Wk, xb, VT, eb, ET, WqT, WkT);
  phase1_k<<<576, 256, 0, stream>>>(VT, ET, WqT, WkT, M, W2T);
  phase2_k<<<512, 256, 0, stream>>>(M, W2T, R);
  phase3_k<<<1024, 256, 0, stream>>>(xb, eb, R, out);
}

// Round 10
// 105.239 us; speedup vs baseline: 1.2077x; 1.0079x over previous
//
#include <hip/hip_runtime.h>
#include <hip/hip_bf16.h>

// Problem constants
#define DIM_X 256
#define DIM_E 256
#define DD    512          // DIM_X + DIM_E
#define NB    8            // batch
#define NN    2048         // sequence
#define SCALE 0.044194173824159216f   // (DIM_X+DIM_E)^-0.5

typedef __attribute__((ext_vector_type(8))) __bf16 bf16x8;
typedef __attribute__((ext_vector_type(4))) float  f32x4;
using bf16 = __hip_bfloat16;

__device__ __forceinline__ unsigned short f2bf(float f) {
  union { __hip_bfloat16 h; unsigned short u; } c;
  c.h = __float2bfloat16(f);
  return c.u;
}

// async global->LDS 16B copy. LDS dest must be wave-uniform base + lane*16.
__device__ __forceinline__ void async_lds16(const void* g, void* l) {
  using u32_as3 = __attribute__((address_space(3))) unsigned int;
  using u32_as1 = const __attribute__((address_space(1))) unsigned int;
  __builtin_amdgcn_global_load_lds(
      reinterpret_cast<u32_as1*>(reinterpret_cast<unsigned long long>(g)),
      reinterpret_cast<u32_as3*>(static_cast<unsigned int>(
          reinterpret_cast<unsigned long long>(l))),
      16, 0, 0);
}

// ---------------------------------------------------------------------------
// pack: 5120 32x32-tile jobs over 1024 blocks (5 each):
//   jobs [0,4096):     x -> xb (straight bf16) + VT (transpose)
//   jobs [4096,4608):  e -> eb (straight) + ET (transpose)
//   jobs [4608,4864):  Wq -> WqT (transpose)
//   jobs [4864,5120):  Wk -> WkT (transpose)
// ---------------------------------------------------------------------------
__global__ __launch_bounds__(256, 4) void pack_k(
    const float* __restrict__ x, const float* __restrict__ e,
    const float* __restrict__ Wq, const float* __restrict__ Wk, bf16* xb,
    bf16* VT, bf16* eb, bf16* ET, bf16* WqT, bf16* WkT) {
  __shared__ float tile[32][33];
  const int tid  = threadIdx.x;
  const int lrow = tid >> 3;        // 0..31 (load row)
  const int lc4  = (tid & 7) * 4;   // float4 col
  for (int j = blockIdx.x; j < 5120; j += 1024) {
    const float* src; int ld;
    bf16 *dS = nullptr, *dT; int ldS = 0, ldT;
    if (j < 4096) {
      int b = j >> 9, r = (j >> 3) & 63, c = j & 7;
      src = x + ((long)b * NN + r * 32) * DIM_X + c * 32; ld = DIM_X;
      dS = xb + ((long)b * NN + r * 32) * DIM_X + c * 32; ldS = DIM_X;
      dT = VT + ((long)b * DIM_X + c * 32) * NN + r * 32; ldT = NN;
    } else if (j < 4608) {
      int i = j - 4096, r = i >> 3, c = i & 7;
      src = e + ((long)r * 32) * DIM_E + c * 32; ld = DIM_E;
      dS = eb + ((long)r * 32) * DIM_E + c * 32; ldS = DIM_E;
      dT = ET + ((long)c * 32) * NN + r * 32; ldT = NN;
    } else if (j < 4864) {
      int i = j - 4608, r = i >> 4, c = i & 15;
      src = Wq + ((long)r * 32) * DD + c * 32; ld = DD;
      dT = WqT + ((long)c * 32) * DD + r * 32; ldT = DD;
    } else {
      int i = j - 4864, r = i >> 4, c = i & 15;
      src = Wk + ((long)r * 32) * DD + c * 32; ld = DD;
      dT = WkT + ((long)c * 32) * DD + r * 32; ldT = DD;
    }
    float4 v = *(const float4*)(src + (long)lrow * ld + lc4);
    if (dS) {
      ushort4 o;
      o.x = f2bf(v.x); o.y = f2bf(v.y); o.z = f2bf(v.z); o.w = f2bf(v.w);
      *(ushort4*)((unsigned short*)dS + (long)lrow * ldS + lc4) = o;
    }
    tile[lrow][lc4 + 0] = v.x; tile[lrow][lc4 + 1] = v.y;
    tile[lrow][lc4 + 2] = v.z; tile[lrow][lc4 + 3] = v.w;
    __syncthreads();
    {
      ushort4 o;
      o.x = f2bf(tile[lc4 + 0][lrow]);
      o.y = f2bf(tile[lc4 + 1][lrow]);
      o.z = f2bf(tile[lc4 + 2][lrow]);
      o.w = f2bf(tile[lc4 + 3][lrow]);
      *(ushort4*)((unsigned short*)dT + (long)lrow * ldT + lc4) = o;
    }
    __syncthreads();
  }
}

// ---------------------------------------------------------------------------
// One BMxBN tile of C = alpha * A @ B^T (operands K-major bf16).
// 4 waves 2x2, wave tile (BM/2)x(BN/2), 16x16x32 MFMA, XOR-swizzled LDS,
// global_load_lds width-16 staging, K-tile BKt.
// A1 (if non-null): A columns k>=256 (same leading dim as A0).
// ---------------------------------------------------------------------------
template <int BM, int BN, int BKt, bool OUT_BF16>
__device__ void gemm_tile(const bf16* __restrict__ A0,
                          const bf16* __restrict__ A1,
                          const bf16* __restrict__ B, void* __restrict__ Cv,
                          int K, int lda, int ldb, int ldc, float alpha,
                          char* smem) {
  constexpr int CPT = BKt / 8;       // 16B chunks per row
  constexpr int KS  = BKt / 32;      // MFMA k-steps per staged tile
  constexpr int WTM = BM / 2, WTN = BN / 2;
  constexpr int IM = WTM / 16, IN = WTN / 16;
  constexpr int CA = BM * CPT, CB = BN * CPT;
  bf16* sA = (bf16*)smem;
  bf16* sB = (bf16*)(smem + (size_t)BM * BKt * 2);

  const int tid  = threadIdx.x;
  const int lane = tid & 63;
  const int wave = tid >> 6;
  const int lm   = lane & 15;
  const int quad = lane >> 4;
  const int wm   = (wave >> 1) * WTM;
  const int wn   = (wave & 1) * WTN;

  f32x4 acc[IM][IN];
#pragma unroll
  for (int i = 0; i < IM; i++)
#pragma unroll
    for (int j = 0; j < IN; j++) acc[i][j] = (f32x4){0.f, 0.f, 0.f, 0.f};

  for (int k0 = 0; k0 < K; k0 += BKt) {
    const bf16* Ak = A0; int kk = k0;
    if (A1 != nullptr && k0 >= 256) { Ak = A1; kk = k0 - 256; }
#pragma unroll
    for (int c = tid; c < CA; c += 256) {
      int row = c / CPT;
      int cb  = (c % CPT) ^ (row % CPT);
      async_lds16(Ak + (long)row * lda + kk + cb * 8, sA + (size_t)c * 8);
    }
#pragma unroll
    for (int c = tid; c < CB; c += 256) {
      int row = c / CPT;
      int cb  = (c % CPT) ^ (row % CPT);
      async_lds16(B + (long)row * ldb + k0 + cb * 8, sB + (size_t)c * 8);
    }
    __syncthreads();  // drains vmcnt (global_load_lds)

    bf16x8 af[KS][IM], bfr[KS][IN];
#pragma unroll
    for (int s = 0; s < KS; s++) {
#pragma unroll
      for (int i = 0; i < IM; i++) {
        int r = wm + i * 16 + lm;
        af[s][i] = *(const bf16x8*)&sA[r * BKt +
                                       (((s * 4 + quad) ^ (r % CPT)) * 8)];
      }
#pragma unroll
      for (int j = 0; j < IN; j++) {
        int r = wn + j * 16 + lm;
        bfr[s][j] = *(const bf16x8*)&sB[r * BKt +
                                        (((s * 4 + quad) ^ (r % CPT)) * 8)];
      }
    }
#pragma unroll
    for (int s = 0; s < KS; s++)
#pragma unroll
      for (int i = 0; i < IM; i++)
#pragma unroll
        for (int j = 0; j < IN; j++)
          acc[i][j] = __builtin_amdgcn_mfma_f32_16x16x32_bf16(
              af[s][i], bfr[s][j], acc[i][j], 0, 0, 0);
    __syncthreads();
  }

  // C/D layout (16x16): col = lane&15, row = (lane>>4)*4 + reg  [m89-verified]
  const int baseRow = wm + quad * 4;
  const int baseCol = wn + lm;
  if (OUT_BF16) {
    bf16* Cb = (bf16*)Cv;
#pragma unroll
    for (int i = 0; i < IM; i++)
#pragma unroll
      for (int r = 0; r < 4; r++) {
        int row = baseRow + i * 16 + r;
#pragma unroll
        for (int j = 0; j < IN; j++)
          Cb[(long)row * ldc + baseCol + j * 16] =
              __float2bfloat16(acc[i][j][r] * alpha);
      }
  } else {
    float* Cf = (float*)Cv;
#pragma unroll
    for (int i = 0; i < IM; i++)
#pragma unroll
      for (int r = 0; r < 4; r++) {
        int row = baseRow + i * 16 + r;
#pragma unroll
        for (int j = 0; j < IN; j++)
          Cf[(long)row * ldc + baseCol + j * 16] = acc[i][j][r] * alpha;
      }
  }
}

// ---------------------------------------------------------------------------
// phase1 (576 blocks): M_b = VT_b @ [VT_b ; ET]^T  (512 jobs, 32x64, K=2048,
//   BK=128, XCD-swizzled b=bx&7 so VT_b (4MB) stays in one XCD's L2;
//   2+ blocks/CU for latency hiding)
//   + W2T = WqT @ WkT^T (64 jobs, 64x64, K=512)
// ---------------------------------------------------------------------------
__global__ __launch_bounds__(256, 4) void phase1_k(const bf16* VT,
                                                   const bf16* ET,
                                                   const bf16* WqT,
                                                   const bf16* WkT, bf16* M,
                                                   bf16* W2T) {
  __shared__ __align__(16) char smem[32768];
  const int bx = blockIdx.x;
  if (bx < 512) {
    int b = bx & 7, r = (bx >> 3) & 7, c = bx >> 6;
    const bf16* A = VT + (long)b * DIM_X * NN + (long)r * 32 * NN;
    const bf16* B = (c < 4) ? VT + (long)b * DIM_X * NN + (long)c * 64 * NN
                            : ET + (long)(c - 4) * 64 * NN;
    gemm_tile<32, 64, 128, true>(
        A, nullptr, B, M + (long)b * DIM_X * DD + (long)r * 32 * DD + c * 64,
        NN, NN, NN, DD, 1.0f, smem);
  } else {
    int i = bx - 512, r2 = i >> 3, c2 = i & 7;
    gemm_tile<64, 64, 128, true>(WqT + (long)r2 * 64 * DD, nullptr,
                                 WkT + (long)c2 * 64 * DD,
                                 W2T + (long)r2 * 64 * DD + c2 * 64, DD, DD,
                                 DD, DD, 1.0f, smem);
  }
}

// phase2 (512 blocks): R_b = SCALE * M_b @ W2T^T (32x64 tiles, K=512, BK=128)
__global__ __launch_bounds__(256, 4) void phase2_k(const bf16* M,
                                                   const bf16* W2T, bf16* R) {
  __shared__ __align__(16) char smem[32768];
  const int bx = blockIdx.x;
  int b = bx & 7, r = (bx >> 3) & 7, c = bx >> 6;
  gemm_tile<32, 64, 128, true>(
      M + (long)b * DIM_X * DD + (long)r * 32 * DD, nullptr,
      W2T + (long)c * 64 * DD,
      R + (long)b * DIM_X * DD + (long)r * 32 * DD + c * 64, DD, DD, DD, DD,
      SCALE, smem);
}

// ---------------------------------------------------------------------------
// phase3 (512 blocks): out_b = [xb_b | eb] @ R_b^T (64x128 tiles, K=512,
//   fp32 out). 64x128 halves A-slab fetch redundancy vs 64x64 (98 MB vs
//   134 MB L2 traffic) and doubles MFMA per staged tile. LDS 48 KB ->
//   3 blocks/CU cap, 2/CU at 512 blocks. XCD-swizzled b=bx&7.
// ---------------------------------------------------------------------------
__global__ __launch_bounds__(256, 3) void phase3_k(const bf16* xb,
                                                   const bf16* eb,
                                                   const bf16* R, float* out) {
  __shared__ __align__(16) char smem[49152];
  const int bx = blockIdx.x;
  int b = bx & 7, m = (bx >> 3) & 31, n = (bx >> 8) & 1;
  gemm_tile<64, 128, 128, false>(
      xb + (long)b * NN * DIM_X + (long)m * 64 * DIM_X,
      eb + (long)m * 64 * DIM_E,
      R + (long)b * DIM_X * DD + (long)n * 128 * DD,
      out + (long)b * NN * DIM_X + (long)m * 64 * DIM_X + n * 128, DD, DIM_X,
      DD, DIM_X, 1.0f, smem);
}

// ---------------------------------------------------------------------------

extern "C" void kernel_launch(void* const* d_in, const int* in_sizes, int n_in,
                              void* d_out, int out_size, void* d_ws,
                              size_t ws_size, hipStream_t stream) {
  const float* x  = (const float*)d_in[0];  // (8, 2048, 256)
  const float* e  = (const float*)d_in[1];  // (2048, 256)
  const float* Wq = (const float*)d_in[2];  // (512, 512)
  const float* Wk = (const float*)d_in[3];  // (512, 512)
  float* out = (float*)d_out;               // (8, 2048, 256)

  char* ws = (char*)d_ws;
  size_t off = 0;
  auto alloc = [&](size_t bytes) {
    void* p = ws + off;
    off += (bytes + 255) & ~(size_t)255;
    return p;
  };

  bf16* xb  = (bf16*)alloc((size_t)NB * NN * DIM_X * 2);  // 8.4 MB
  bf16* VT  = (bf16*)alloc((size_t)NB * DIM_X * NN * 2);  // 8.4 MB
  bf16* eb  = (bf16*)alloc((size_t)NN * DIM_E * 2);       // 1 MB
  bf16* ET  = (bf16*)alloc((size_t)DIM_E * NN * 2);       // 1 MB
  bf16* WqT = (bf16*)alloc((size_t)DD * DD * 2);          // 0.5 MB
  bf16* WkT = (bf16*)alloc((size_t)DD * DD * 2);          // 0.5 MB
  bf16* W2T = (bf16*)alloc((size_t)DD * DD * 2);          // 0.5 MB
  bf16* M   = (bf16*)alloc((size_t)NB * DIM_X * DD * 2);  // 2 MB
  bf16* R   = (bf16*)alloc((size_t)NB * DIM_X * DD * 2);  // 2 MB

  pack_k<<<1024, 256, 0, stream>>>(x, e, Wq, Wk, xb, VT, eb, ET, WqT, WkT);
  phase1_k<<<576, 256, 0, stream>>>(VT, ET, WqT, WkT, M, W2T);
  phase2_k<<<512, 256, 0, stream>>>(M, W2T, R);
  phase3_k<<<512, 256, 0, stream>>>(xb, eb, R, out);
}